// Round 2
// baseline (401.020 us; speedup 1.0000x reference)
//
#include <hip/hip_runtime.h>
#include <math.h>

// MERITS_T: dead-code-eliminated forward.
// B=1024 T=25 MED=145 LAB=1956 GLU=16 D=64 H=32 HID=1160
#define B_   1024
#define T_   25
#define MED_ 145
#define LAB_ 1956
#define GLU_ 16
#define D_   64
#define H_   32
#define HID_ 1160

// ---------------------------------------------------------------------------
// K1: static = relu(relu(lab @ w1 + b1) @ w2 + b2)   (B,32)
// 4 rows per block, 512 threads (8 k-slices x 64 cols).
__global__ __launch_bounds__(512) void k_static(
    const float* __restrict__ lab, const float* __restrict__ w1,
    const float* __restrict__ b1, const float* __restrict__ w2,
    const float* __restrict__ b2, float* __restrict__ st) {
  const int b0 = blockIdx.x * 4;
  const int col = threadIdx.x & 63;
  const int slice = threadIdx.x >> 6;  // 0..7
  const float* r0 = lab + (size_t)b0 * LAB_;
  float a0 = 0.f, a1 = 0.f, a2 = 0.f, a3 = 0.f;
  for (int k = slice; k < LAB_; k += 8) {
    float w = w1[(size_t)k * D_ + col];
    a0 = fmaf(r0[k], w, a0);
    a1 = fmaf(r0[LAB_ + k], w, a1);
    a2 = fmaf(r0[2 * LAB_ + k], w, a2);
    a3 = fmaf(r0[3 * LAB_ + k], w, a3);
  }
  __shared__ float red[4][8][64];
  red[0][slice][col] = a0;
  red[1][slice][col] = a1;
  red[2][slice][col] = a2;
  red[3][slice][col] = a3;
  __syncthreads();
  __shared__ float t1[4][64];
  if (threadIdx.x < 256) {
    int r = threadIdx.x >> 6, d = threadIdx.x & 63;
    float v = b1[d];
    #pragma unroll
    for (int s2 = 0; s2 < 8; ++s2) v += red[r][s2][d];
    t1[r][d] = fmaxf(v, 0.f);
  }
  __syncthreads();
  if (threadIdx.x < 128) {
    int r = threadIdx.x >> 5, j = threadIdx.x & 31;
    float s = b2[j];
    #pragma unroll 8
    for (int d = 0; d < D_; ++d) s = fmaf(t1[r][d], w2[d * H_ + j], s);
    st[(size_t)(b0 + r) * H_ + j] = fmaxf(s, 0.f);
  }
}

// ---------------------------------------------------------------------------
// K2: W1cT[j*64+d] = sum_m out_w1[(m*64+d)*1160 + j]   (tile-collapse of out_w1)
__global__ __launch_bounds__(256) void k_w1c(const float* __restrict__ w1,
                                             float* __restrict__ w1ct) {
  int idx = blockIdx.x * 256 + threadIdx.x;  // 64*1160 = 74240 = 290*256
  if (idx >= D_ * HID_) return;
  int d = idx / HID_, j = idx - d * HID_;
  const float* p = w1 + (size_t)d * HID_ + j;
  float s = 0.f;
  #pragma unroll 8
  for (int m = 0; m < MED_; ++m) s += p[(size_t)m * D_ * HID_];
  w1ct[(size_t)j * D_ + d] = s;
}

// ---------------------------------------------------------------------------
// K3: w2t[n*1160+j] = out_w2[j*145+n]
__global__ __launch_bounds__(256) void k_w2t(const float* __restrict__ w2,
                                             float* __restrict__ w2t) {
  int idx = blockIdx.x * 256 + threadIdx.x;
  if (idx < HID_ * MED_) {
    int j = idx / MED_, n = idx - j * MED_;
    w2t[(size_t)n * HID_ + j] = w2[idx];
  }
}

// ---------------------------------------------------------------------------
// K4: per-batch fused: glu gating -> patient, q0 (med row 0), 1-query MHA (m1),
//     r = (e0 @ m2_wv) @ m2_wo, rr = relu(r).  One block per b.
__global__ __launch_bounds__(256) void k_perb(
    const float* __restrict__ glu, const float* __restrict__ tf,
    const float* __restrict__ med, const float* __restrict__ st,
    const float* __restrict__ glu_w, const float* __restrict__ glu_b,
    const float* __restrict__ glu_gate, const float* __restrict__ med_w,
    const float* __restrict__ med_b, const float* __restrict__ med_gate,
    const float* __restrict__ wq, const float* __restrict__ wk,
    const float* __restrict__ wv, const float* __restrict__ wo,
    const float* __restrict__ m2wv, const float* __restrict__ m2wo,
    float* __restrict__ rr) {
  const int b = blockIdx.x;
  const int tid = threadIdx.x;
  __shared__ float xin_s[T_][2 * GLU_];
  __shared__ float y_s[T_][H_];
  __shared__ float gate_s[T_];
  __shared__ float medrow_s[MED_];
  __shared__ float pat_s[T_][D_];
  __shared__ float q0_s[D_];
  __shared__ float qh_s[D_];
  __shared__ float kh_s[T_][D_];
  __shared__ float vh_s[T_][D_];
  __shared__ float sc_s[4][T_];
  __shared__ float at_s[4][T_];
  __shared__ float o_s[D_];
  __shared__ float e0_s[D_];
  __shared__ float t2_s[D_];

  // stage glu/time_feat rows and med row t=0
  for (int e = tid; e < T_ * GLU_; e += 256) {
    int t = e >> 4, i = e & 15;
    xin_s[t][i] = glu[((size_t)b * T_ + t) * GLU_ + i];
    xin_s[t][GLU_ + i] = tf[((size_t)b * T_ + t) * GLU_ + i];
  }
  if (tid < MED_) medrow_s[tid] = med[(size_t)b * T_ * MED_ + tid];
  __syncthreads();

  // y = tanh(xin @ glu_w + glu_b)
  for (int e = tid; e < T_ * H_; e += 256) {
    int t = e >> 5, j = e & 31;
    float s = glu_b[j];
    #pragma unroll 8
    for (int i = 0; i < 2 * GLU_; ++i) s = fmaf(xin_s[t][i], glu_w[i * H_ + j], s);
    y_s[t][j] = tanhf(s);
  }
  __syncthreads();

  // per-t sigmoid gate (wave 0) and q0 (wave 1)
  if (tid < T_) {
    float s = 0.f;
    #pragma unroll 8
    for (int j = 0; j < H_; ++j) s = fmaf(y_s[tid][j], glu_gate[j], s);
    gate_s[tid] = 1.f / (1.f + __expf(-s));
  }
  if (tid >= 64 && tid < 128) {
    int d = tid - 64;
    float x = med_b[d];
    for (int m = 0; m < MED_; ++m)
      if (medrow_s[m] > 0.9f) x += med_w[m * D_ + d];
    float v = x * med_gate[d];
    #pragma unroll
    for (int off = 32; off > 0; off >>= 1) v += __shfl_xor(v, off);
    q0_s[d] = x * (1.f / (1.f + __expf(-v)));
  }
  __syncthreads();

  // patient = [glu_rep | static]
  for (int e = tid; e < T_ * H_; e += 256) {
    int t = e >> 5, j = e & 31;
    pat_s[t][j] = y_s[t][j] * gate_s[t];
    pat_s[t][H_ + j] = st[(size_t)b * H_ + j];
  }
  __syncthreads();

  // kh, vh (25x64 each) and qh (64)
  for (int e = tid; e < T_ * D_; e += 256) {
    int t = e >> 6, d = e & 63;
    float sk = 0.f, sv = 0.f;
    #pragma unroll 8
    for (int j = 0; j < D_; ++j) {
      float p = pat_s[t][j];
      sk = fmaf(p, wk[j * D_ + d], sk);
      sv = fmaf(p, wv[j * D_ + d], sv);
    }
    kh_s[t][d] = sk;
    vh_s[t][d] = sv;
  }
  if (tid < D_) {
    float s = 0.f;
    #pragma unroll 8
    for (int j = 0; j < D_; ++j) s = fmaf(q0_s[j], wq[j * D_ + tid], s);
    qh_s[tid] = s;
  }
  __syncthreads();

  // scores (4 heads x 25 keys), scale 1/sqrt(16)
  if (tid < 4 * T_) {
    int h = tid / T_, t = tid - h * T_;
    float s = 0.f;
    #pragma unroll
    for (int i = 0; i < 16; ++i) s = fmaf(qh_s[h * 16 + i], kh_s[t][h * 16 + i], s);
    sc_s[h][t] = s * 0.25f;
  }
  __syncthreads();
  if (tid < 4) {
    float m = -1e30f;
    for (int t = 0; t < T_; ++t) m = fmaxf(m, sc_s[tid][t]);
    float sum = 0.f;
    for (int t = 0; t < T_; ++t) {
      float e = __expf(sc_s[tid][t] - m);
      at_s[tid][t] = e;
      sum += e;
    }
    float inv = 1.f / sum;
    for (int t = 0; t < T_; ++t) at_s[tid][t] *= inv;
  }
  __syncthreads();
  if (tid < D_) {
    int h = tid >> 4;
    float s = 0.f;
    #pragma unroll
    for (int t = 0; t < T_; ++t) s = fmaf(at_s[h][t], vh_s[t][tid], s);
    o_s[tid] = s;
  }
  __syncthreads();
  if (tid < D_) {
    float s = 0.f;
    #pragma unroll 8
    for (int j = 0; j < D_; ++j) s = fmaf(o_s[j], wo[j * D_ + tid], s);
    e0_s[tid] = s;
  }
  __syncthreads();
  if (tid < D_) {
    float s = 0.f;
    #pragma unroll 8
    for (int j = 0; j < D_; ++j) s = fmaf(e0_s[j], m2wv[j * D_ + tid], s);
    t2_s[tid] = s;
  }
  __syncthreads();
  if (tid < D_) {
    float s = 0.f;
    #pragma unroll 8
    for (int j = 0; j < D_; ++j) s = fmaf(t2_s[j], m2wo[j * D_ + tid], s);
    rr[(size_t)b * D_ + tid] = fmaxf(s, 0.f);  // relu(r)
  }
}

// ---------------------------------------------------------------------------
// K5: hid = relu(rr @ W1cT^T + b1); out = hid @ w2 + b2.
// 4 rows per block, 512 threads, grid 256.
__global__ __launch_bounds__(512) void k_final(
    const float* __restrict__ rr, const float* __restrict__ w1ct,
    const float* __restrict__ b1, const float* __restrict__ w2t,
    const float* __restrict__ b2, float* __restrict__ out) {
  __shared__ float rr_s[4][64];
  __shared__ float hid_s[4][HID_];
  const int tid = threadIdx.x;
  const int b0 = blockIdx.x * 4;
  if (tid < 256) rr_s[tid >> 6][tid & 63] = rr[(size_t)b0 * 64 + tid];
  __syncthreads();
  // phase 1: hid tile (4 x 1160)
  for (int e = tid; e < 4 * HID_; e += 512) {
    int r = e / HID_, j = e - r * HID_;
    const float4* wp = (const float4*)(w1ct + (size_t)j * D_);
    const float4* rp = (const float4*)(rr_s[r]);
    float s = b1[j];
    #pragma unroll
    for (int q = 0; q < 16; ++q) {
      float4 w = wp[q];
      float4 x = rp[q];
      s += x.x * w.x + x.y * w.y + x.z * w.z + x.w * w.w;
    }
    hid_s[r][j] = fmaxf(s, 0.f);
  }
  __syncthreads();
  // phase 2: thread = (n, row-half), 2 accumulators each
  if (tid < 2 * MED_) {
    int n = tid % MED_, rh = tid / MED_;
    const float4* wp = (const float4*)(w2t + (size_t)n * HID_);
    const float4* h0 = (const float4*)(hid_s[rh * 2 + 0]);
    const float4* h1 = (const float4*)(hid_s[rh * 2 + 1]);
    float s0 = b2[n], s1 = s0;
    #pragma unroll 4
    for (int q = 0; q < HID_ / 4; ++q) {
      float4 w = wp[q];
      float4 a = h0[q];
      s0 += a.x * w.x + a.y * w.y + a.z * w.z + a.w * w.w;
      float4 c = h1[q];
      s1 += c.x * w.x + c.y * w.y + c.z * w.z + c.w * w.w;
    }
    out[(size_t)(b0 + rh * 2 + 0) * MED_ + n] = s0;
    out[(size_t)(b0 + rh * 2 + 1) * MED_ + n] = s1;
  }
}

// ---------------------------------------------------------------------------
extern "C" void kernel_launch(void* const* d_in, const int* in_sizes, int n_in,
                              void* d_out, int out_size, void* d_ws, size_t ws_size,
                              hipStream_t stream) {
  (void)in_sizes; (void)n_in; (void)out_size; (void)ws_size;
  const float* lab      = (const float*)d_in[0];
  const float* glu      = (const float*)d_in[1];
  const float* tf       = (const float*)d_in[2];
  const float* med      = (const float*)d_in[3];
  const float* sll_w1   = (const float*)d_in[7];
  const float* sll_b1   = (const float*)d_in[8];
  const float* sll_w2   = (const float*)d_in[9];
  const float* sll_b2   = (const float*)d_in[10];
  const float* glu_w    = (const float*)d_in[11];
  const float* glu_b    = (const float*)d_in[12];
  const float* glu_gate = (const float*)d_in[13];
  const float* med_w    = (const float*)d_in[14];
  const float* med_b    = (const float*)d_in[15];
  const float* med_gate = (const float*)d_in[16];
  const float* m1_wq    = (const float*)d_in[27];
  const float* m1_wk    = (const float*)d_in[28];
  const float* m1_wv    = (const float*)d_in[29];
  const float* m1_wo    = (const float*)d_in[30];
  const float* m2_wv    = (const float*)d_in[33];
  const float* m2_wo    = (const float*)d_in[34];
  const float* out_w1   = (const float*)d_in[35];
  const float* out_b1   = (const float*)d_in[36];
  const float* out_w2   = (const float*)d_in[37];
  const float* out_b2   = (const float*)d_in[38];
  float* out = (float*)d_out;

  float* ws   = (float*)d_ws;
  float* st   = ws;                      // 1024*32   = 32768
  float* rr   = st + B_ * H_;            // 1024*64   = 65536
  float* w1ct = rr + B_ * D_;            // 1160*64   = 74240
  float* w2t  = w1ct + HID_ * D_;        // 145*1160  = 168200

  hipLaunchKernelGGL(k_static, dim3(B_ / 4), dim3(512), 0, stream,
                     lab, sll_w1, sll_b1, sll_w2, sll_b2, st);
  hipLaunchKernelGGL(k_w1c, dim3((D_ * HID_) / 256), dim3(256), 0, stream,
                     out_w1, w1ct);
  hipLaunchKernelGGL(k_w2t, dim3((HID_ * MED_ + 255) / 256), dim3(256), 0, stream,
                     out_w2, w2t);
  hipLaunchKernelGGL(k_perb, dim3(B_), dim3(256), 0, stream,
                     glu, tf, med, st, glu_w, glu_b, glu_gate,
                     med_w, med_b, med_gate,
                     m1_wq, m1_wk, m1_wv, m1_wo, m2_wv, m2_wo, rr);
  hipLaunchKernelGGL(k_final, dim3(B_ / 4), dim3(512), 0, stream,
                     rr, w1ct, out_b1, w2t, out_b2, out);
}

// Round 3
// 275.964 us; speedup vs baseline: 1.4532x; 1.4532x over previous
//
#include <hip/hip_runtime.h>
#include <math.h>

// MERITS_T: dead-code-eliminated forward.
// B=1024 T=25 MED=145 LAB=1956 GLU=16 D=64 H=32 HID=1160
#define B_   1024
#define T_   25
#define MED_ 145
#define LAB_ 1956
#define GLU_ 16
#define D_   64
#define H_   32
#define HID_ 1160
#define KC_  978   // LAB_/2 per k-chunk

// ---------------------------------------------------------------------------
// K1a: partial GEMM lab @ sll_w1, k-split in 2 chunks. grid (256, 2) x 512.
// part[kc][row][d] = sum_{k in chunk} lab[row,k] * w1[k,d]
__global__ __launch_bounds__(512) void k_static_a(
    const float* __restrict__ lab, const float* __restrict__ w1,
    float* __restrict__ part) {
  const int rg = blockIdx.x;
  const int kc = blockIdx.y;
  const int b0 = rg * 4;
  const int k0 = kc * KC_;
  const int tid = threadIdx.x;
  __shared__ float2 lab_s2[4][KC_ / 2];  // 15.6 KB
  // stage 4 rows x 978 floats, coalesced float2
  for (int e = tid; e < 4 * (KC_ / 2); e += 512) {
    int r = e / (KC_ / 2), i = e - r * (KC_ / 2);
    lab_s2[r][i] = ((const float2*)(lab + (size_t)(b0 + r) * LAB_ + k0))[i];
  }
  __syncthreads();
  const float* lab_f = (const float*)lab_s2;  // [4][978]
  const int col = tid & 63;
  const int slice = tid >> 6;  // 0..7
  float a0 = 0.f, a1 = 0.f, a2 = 0.f, a3 = 0.f;
  #pragma unroll 4
  for (int k = slice; k < KC_; k += 8) {
    float w = w1[(size_t)(k0 + k) * D_ + col];
    a0 = fmaf(lab_f[k], w, a0);
    a1 = fmaf(lab_f[KC_ + k], w, a1);
    a2 = fmaf(lab_f[2 * KC_ + k], w, a2);
    a3 = fmaf(lab_f[3 * KC_ + k], w, a3);
  }
  __syncthreads();
  __shared__ float red[4][8][64];  // 8 KB
  red[0][slice][col] = a0;
  red[1][slice][col] = a1;
  red[2][slice][col] = a2;
  red[3][slice][col] = a3;
  __syncthreads();
  if (tid < 256) {
    int r = tid >> 6, d = tid & 63;
    float v = 0.f;
    #pragma unroll
    for (int s2 = 0; s2 < 8; ++s2) v += red[r][s2][d];
    part[(size_t)kc * B_ * D_ + (size_t)(b0 + r) * D_ + d] = v;
  }
}

// K1b: combine partials, bias+relu, second layer (64->32), relu. grid 256 x 256.
__global__ __launch_bounds__(256) void k_static_b(
    const float* __restrict__ part, const float* __restrict__ b1,
    const float* __restrict__ w2, const float* __restrict__ b2,
    float* __restrict__ st) {
  const int b0 = blockIdx.x * 4;
  const int tid = threadIdx.x;
  __shared__ float t1[4][64];
  {
    int r = tid >> 6, d = tid & 63;
    size_t o = (size_t)(b0 + r) * D_ + d;
    float v = part[o] + part[(size_t)B_ * D_ + o] + b1[d];
    t1[r][d] = fmaxf(v, 0.f);
  }
  __syncthreads();
  if (tid < 128) {
    int r = tid >> 5, j = tid & 31;
    float s = b2[j];
    #pragma unroll 8
    for (int d = 0; d < D_; ++d) s = fmaf(t1[r][d], w2[d * H_ + j], s);
    st[(size_t)(b0 + r) * H_ + j] = fmaxf(s, 0.f);
  }
}

// ---------------------------------------------------------------------------
// K2: w1c[d*1160+j] += sum_{m in quarter} out_w1[m*74240 + d*1160 + j]
// grid (290, 4) x 256; w1c zero-initialized by memset. Loads & atomics coalesced.
__global__ __launch_bounds__(256) void k_w1c(const float* __restrict__ w1,
                                             float* __restrict__ w1c) {
  const int idx = blockIdx.x * 256 + threadIdx.x;  // 0..74239 (=290*256)
  const int mq = blockIdx.y;                       // 0..3
  const int m0 = (mq * MED_) >> 2, m1 = ((mq + 1) * MED_) >> 2;
  const float* p = w1 + idx + (size_t)m0 * D_ * HID_;
  float s = 0.f;
  #pragma unroll 8
  for (int m = m0; m < m1; ++m) {
    s += *p;
    p += (size_t)D_ * HID_;
  }
  atomicAdd(&w1c[idx], s);
}

// ---------------------------------------------------------------------------
// K4: per-batch fused: glu gating -> patient, q0, 1-query 4-head MHA (m1),
//     rr = relu((e0 @ m2_wv) @ m2_wo). One block (256 thr) per b.
__global__ __launch_bounds__(256) void k_perb(
    const float* __restrict__ glu, const float* __restrict__ tf,
    const float* __restrict__ med, const float* __restrict__ st,
    const float* __restrict__ glu_w, const float* __restrict__ glu_b,
    const float* __restrict__ glu_gate, const float* __restrict__ med_w,
    const float* __restrict__ med_b, const float* __restrict__ med_gate,
    const float* __restrict__ wq, const float* __restrict__ wk,
    const float* __restrict__ wv, const float* __restrict__ wo,
    const float* __restrict__ m2wv, const float* __restrict__ m2wo,
    float* __restrict__ rr) {
  const int b = blockIdx.x;
  const int tid = threadIdx.x;
  const int d = tid & 63;
  const int s4 = tid >> 6;  // 0..3
  __shared__ float xin_s[T_][2 * GLU_];
  __shared__ float y_s[T_][H_];
  __shared__ float gate_s[T_];
  __shared__ float medrow_s[MED_];
  __shared__ float pat_s[28][D_];   // rows 25..27 zero
  __shared__ float q0_s[D_];
  __shared__ float kh_s[T_][D_];
  __shared__ float vh_s[T_][D_];
  __shared__ float sc_s[4][T_];
  __shared__ float at_s[4][T_];
  __shared__ float o_s[D_];
  __shared__ float vec_s[D_];
  __shared__ float red4[4][D_];

  // stage inputs
  for (int e = tid; e < T_ * GLU_; e += 256) {
    int t = e >> 4, i = e & 15;
    xin_s[t][i] = glu[((size_t)b * T_ + t) * GLU_ + i];
    xin_s[t][GLU_ + i] = tf[((size_t)b * T_ + t) * GLU_ + i];
  }
  if (tid < MED_) medrow_s[tid] = med[(size_t)b * T_ * MED_ + tid];
  __syncthreads();

  // y = tanh(xin @ glu_w + glu_b)
  for (int e = tid; e < T_ * H_; e += 256) {
    int t = e >> 5, j = e & 31;
    float s = glu_b[j];
    #pragma unroll 8
    for (int i = 0; i < 2 * GLU_; ++i) s = fmaf(xin_s[t][i], glu_w[i * H_ + j], s);
    y_s[t][j] = tanhf(s);
  }
  __syncthreads();

  // gate (wave 0) | q0 (wave 1)
  if (tid < T_) {
    float s = 0.f;
    #pragma unroll 8
    for (int j = 0; j < H_; ++j) s = fmaf(y_s[tid][j], glu_gate[j], s);
    gate_s[tid] = 1.f / (1.f + __expf(-s));
  }
  if (tid >= 64 && tid < 128) {
    int dd = tid - 64;
    float x = med_b[dd];
    for (int m = 0; m < MED_; ++m)
      if (medrow_s[m] > 0.9f) x += med_w[m * D_ + dd];
    float v = x * med_gate[dd];
    #pragma unroll
    for (int off = 32; off > 0; off >>= 1) v += __shfl_xor(v, off);
    q0_s[dd] = x * (1.f / (1.f + __expf(-v)));
  }
  __syncthreads();

  // patient = [glu_rep | static], rows 25..27 zeroed
  for (int e = tid; e < 28 * H_; e += 256) {
    int t = e >> 5, j = e & 31;
    if (t < T_) {
      pat_s[t][j] = y_s[t][j] * gate_s[t];
      pat_s[t][H_ + j] = st[(size_t)b * H_ + j];
    } else {
      pat_s[t][j] = 0.f;
      pat_s[t][H_ + j] = 0.f;
    }
  }
  __syncthreads();

  // kh, vh: thread (d, s4), t = s4 + 4i; weight values reused across 7 t's
  {
    float aK[7] = {0.f, 0.f, 0.f, 0.f, 0.f, 0.f, 0.f};
    float aV[7] = {0.f, 0.f, 0.f, 0.f, 0.f, 0.f, 0.f};
    #pragma unroll 4
    for (int j = 0; j < D_; ++j) {
      float wkj = wk[j * D_ + d];
      float wvj = wv[j * D_ + d];
      #pragma unroll
      for (int i = 0; i < 7; ++i) {
        float p = pat_s[s4 + 4 * i][j];
        aK[i] = fmaf(p, wkj, aK[i]);
        aV[i] = fmaf(p, wvj, aV[i]);
      }
    }
    #pragma unroll
    for (int i = 0; i < 7; ++i) {
      int t = s4 + 4 * i;
      if (t < T_) { kh_s[t][d] = aK[i]; vh_s[t][d] = aV[i]; }
    }
  }
  // qh partial (same barrier section; disjoint LDS)
  {
    float qp = 0.f;
    #pragma unroll
    for (int i = 0; i < 16; ++i) {
      int j = s4 * 16 + i;
      qp = fmaf(q0_s[j], wq[j * D_ + d], qp);
    }
    red4[s4][d] = qp;
  }
  __syncthreads();
  if (tid < D_) vec_s[tid] = red4[0][tid] + red4[1][tid] + red4[2][tid] + red4[3][tid];  // qh
  __syncthreads();

  // scores (4 heads x 25 keys), scale 1/sqrt(16)
  if (tid < 4 * T_) {
    int h = tid / T_, t = tid - h * T_;
    float s = 0.f;
    #pragma unroll
    for (int i = 0; i < 16; ++i) s = fmaf(vec_s[h * 16 + i], kh_s[t][h * 16 + i], s);
    sc_s[h][t] = s * 0.25f;
  }
  __syncthreads();
  if (tid < 4) {
    float m = -1e30f;
    for (int t = 0; t < T_; ++t) m = fmaxf(m, sc_s[tid][t]);
    float sum = 0.f;
    for (int t = 0; t < T_; ++t) {
      float e = __expf(sc_s[tid][t] - m);
      at_s[tid][t] = e;
      sum += e;
    }
    float inv = 1.f / sum;
    for (int t = 0; t < T_; ++t) at_s[tid][t] *= inv;
  }
  __syncthreads();
  if (tid < D_) {
    int h = tid >> 4;
    float s = 0.f;
    #pragma unroll
    for (int t = 0; t < T_; ++t) s = fmaf(at_s[h][t], vh_s[t][tid], s);
    o_s[tid] = s;
  }
  __syncthreads();
  // e0 = o @ wo  (widened: 4 slices x 16)
  {
    float p = 0.f;
    #pragma unroll
    for (int i = 0; i < 16; ++i) {
      int j = s4 * 16 + i;
      p = fmaf(o_s[j], wo[j * D_ + d], p);
    }
    red4[s4][d] = p;
  }
  __syncthreads();
  if (tid < D_) vec_s[tid] = red4[0][tid] + red4[1][tid] + red4[2][tid] + red4[3][tid];  // e0
  __syncthreads();
  // t2 = e0 @ m2wv
  {
    float p = 0.f;
    #pragma unroll
    for (int i = 0; i < 16; ++i) {
      int j = s4 * 16 + i;
      p = fmaf(vec_s[j], m2wv[j * D_ + d], p);
    }
    red4[s4][d] = p;
  }
  __syncthreads();
  if (tid < D_) o_s[tid] = red4[0][tid] + red4[1][tid] + red4[2][tid] + red4[3][tid];  // t2
  __syncthreads();
  // rr = relu(t2 @ m2wo)
  {
    float p = 0.f;
    #pragma unroll
    for (int i = 0; i < 16; ++i) {
      int j = s4 * 16 + i;
      p = fmaf(o_s[j], m2wo[j * D_ + d], p);
    }
    red4[s4][d] = p;
  }
  __syncthreads();
  if (tid < D_) {
    float v = red4[0][tid] + red4[1][tid] + red4[2][tid] + red4[3][tid];
    rr[(size_t)b * D_ + tid] = fmaxf(v, 0.f);
  }
}

// ---------------------------------------------------------------------------
// K5: hid = relu(rr @ w1c + b1) (K=64); out = hid @ out_w2 + b2 (K=1160).
// 2 rows/block, grid 512, 640 threads. w1c layout [d][j]; out_w2 read directly.
__global__ __launch_bounds__(640) void k_final(
    const float* __restrict__ rr, const float* __restrict__ w1c,
    const float* __restrict__ b1, const float* __restrict__ w2,
    const float* __restrict__ b2, float* __restrict__ out) {
  __shared__ float rr_s[2][D_];
  __shared__ float hid_s[2][HID_];
  __shared__ float p2_s[2][2][152];
  const int tid = threadIdx.x;
  const int b0 = blockIdx.x * 2;
  if (tid < 128) rr_s[tid >> 6][tid & 63] = rr[(size_t)b0 * D_ + tid];
  __syncthreads();
  // phase 1: hid (2 x 1160); lanes vary j -> w1c loads coalesced
  for (int e = tid; e < 2 * HID_; e += 640) {
    int r = e / HID_, j = e - r * HID_;
    float s = b1[j];
    #pragma unroll 8
    for (int dd = 0; dd < D_; ++dd) s = fmaf(rr_s[r][dd], w1c[(size_t)dd * HID_ + j], s);
    hid_s[r][j] = fmaxf(s, 0.f);
  }
  __syncthreads();
  // phase 2: thread (h, rh, n); j-half per h; w2 reads coalesced over n
  if (tid < 580) {
    int h = tid / 290, rem = tid - h * 290;
    int rh = rem / MED_, n = rem - rh * MED_;
    const float* hp = hid_s[rh] + h * 580;
    const float* wp = w2 + (size_t)h * 580 * MED_ + n;
    float s = 0.f;
    #pragma unroll 8
    for (int j = 0; j < 580; ++j) s = fmaf(hp[j], wp[(size_t)j * MED_], s);
    p2_s[h][rh][n] = s;
  }
  __syncthreads();
  if (tid < 2 * MED_) {
    int rh = tid / MED_, n = tid - rh * MED_;
    out[(size_t)(b0 + rh) * MED_ + n] = p2_s[0][rh][n] + p2_s[1][rh][n] + b2[n];
  }
}

// ---------------------------------------------------------------------------
extern "C" void kernel_launch(void* const* d_in, const int* in_sizes, int n_in,
                              void* d_out, int out_size, void* d_ws, size_t ws_size,
                              hipStream_t stream) {
  (void)in_sizes; (void)n_in; (void)out_size; (void)ws_size;
  const float* lab      = (const float*)d_in[0];
  const float* glu      = (const float*)d_in[1];
  const float* tf       = (const float*)d_in[2];
  const float* med      = (const float*)d_in[3];
  const float* sll_w1   = (const float*)d_in[7];
  const float* sll_b1   = (const float*)d_in[8];
  const float* sll_w2   = (const float*)d_in[9];
  const float* sll_b2   = (const float*)d_in[10];
  const float* glu_w    = (const float*)d_in[11];
  const float* glu_b    = (const float*)d_in[12];
  const float* glu_gate = (const float*)d_in[13];
  const float* med_w    = (const float*)d_in[14];
  const float* med_b    = (const float*)d_in[15];
  const float* med_gate = (const float*)d_in[16];
  const float* m1_wq    = (const float*)d_in[27];
  const float* m1_wk    = (const float*)d_in[28];
  const float* m1_wv    = (const float*)d_in[29];
  const float* m1_wo    = (const float*)d_in[30];
  const float* m2_wv    = (const float*)d_in[33];
  const float* m2_wo    = (const float*)d_in[34];
  const float* out_w1   = (const float*)d_in[35];
  const float* out_b1   = (const float*)d_in[36];
  const float* out_w2   = (const float*)d_in[37];
  const float* out_b2   = (const float*)d_in[38];
  float* out = (float*)d_out;

  float* ws   = (float*)d_ws;
  float* st   = ws;                      // 1024*32   = 32768
  float* rr   = st + B_ * H_;            // 1024*64   = 65536
  float* w1c  = rr + B_ * D_;            // 64*1160   = 74240
  float* part = w1c + D_ * HID_;         // 2*1024*64 = 131072

  hipLaunchKernelGGL(k_static_a, dim3(B_ / 4, 2), dim3(512), 0, stream,
                     lab, sll_w1, part);
  hipLaunchKernelGGL(k_static_b, dim3(B_ / 4), dim3(256), 0, stream,
                     part, sll_b1, sll_w2, sll_b2, st);
  hipMemsetAsync(w1c, 0, (size_t)D_ * HID_ * sizeof(float), stream);
  hipLaunchKernelGGL(k_w1c, dim3((D_ * HID_) / 256, 4), dim3(256), 0, stream,
                     out_w1, w1c);
  hipLaunchKernelGGL(k_perb, dim3(B_), dim3(256), 0, stream,
                     glu, tf, med, st, glu_w, glu_b, glu_gate,
                     med_w, med_b, med_gate,
                     m1_wq, m1_wk, m1_wv, m1_wo, m2_wv, m2_wo, rr);
  hipLaunchKernelGGL(k_final, dim3(B_ / 2), dim3(640), 0, stream,
                     rr, w1c, out_b1, out_w2, out_b2, out);
}

// Round 4
// 244.690 us; speedup vs baseline: 1.6389x; 1.1278x over previous
//
#include <hip/hip_runtime.h>
#include <math.h>

// MERITS_T: dead-code-eliminated forward.
// B=1024 T=25 MED=145 LAB=1956 GLU=16 D=64 H=32 HID=1160
#define B_   1024
#define T_   25
#define MED_ 145
#define LAB_ 1956
#define GLU_ 16
#define D_   64
#define H_   32
#define HID_ 1160
#define KC_  978   // LAB_/2 per k-chunk

// ---------------------------------------------------------------------------
// K1a: partial GEMM lab @ sll_w1, k-split in 2 chunks, 8 rows/block.
// grid (128, 2) x 512.  part[kc][row][d] = sum_{k in chunk} lab[row,k]*w1[k,d]
__global__ __launch_bounds__(512) void k_static_a(
    const float* __restrict__ lab, const float* __restrict__ w1,
    float* __restrict__ part) {
  const int b0 = blockIdx.x * 8;
  const int kc = blockIdx.y;
  const int k0 = kc * KC_;
  const int tid = threadIdx.x;
  __shared__ float2 lab_s2[8][KC_ / 2];  // 31.3 KB
  for (int e = tid; e < 8 * (KC_ / 2); e += 512) {
    int r = e / (KC_ / 2), i = e - r * (KC_ / 2);
    lab_s2[r][i] = ((const float2*)(lab + (size_t)(b0 + r) * LAB_ + k0))[i];
  }
  __syncthreads();
  const float* lab_f = (const float*)lab_s2;  // [8][978]
  const int col = tid & 63;
  const int slice = tid >> 6;  // 0..7
  float acc[8] = {0.f, 0.f, 0.f, 0.f, 0.f, 0.f, 0.f, 0.f};
  #pragma unroll 2
  for (int k = slice; k < KC_; k += 8) {
    float w = w1[(size_t)(k0 + k) * D_ + col];
    #pragma unroll
    for (int r = 0; r < 8; ++r) acc[r] = fmaf(lab_f[r * KC_ + k], w, acc[r]);
  }
  __syncthreads();
  __shared__ float red[8][8][64];  // 16 KB
  #pragma unroll
  for (int r = 0; r < 8; ++r) red[r][slice][col] = acc[r];
  __syncthreads();
  {
    int r = tid >> 6, d = tid & 63;
    float v = 0.f;
    #pragma unroll
    for (int s2 = 0; s2 < 8; ++s2) v += red[r][s2][d];
    part[(size_t)kc * B_ * D_ + (size_t)(b0 + r) * D_ + d] = v;
  }
}

// K1b: combine partials, bias+relu, second layer (64->32), relu. grid 256 x 256.
__global__ __launch_bounds__(256) void k_static_b(
    const float* __restrict__ part, const float* __restrict__ b1,
    const float* __restrict__ w2, const float* __restrict__ b2,
    float* __restrict__ st) {
  const int b0 = blockIdx.x * 4;
  const int tid = threadIdx.x;
  __shared__ float t1[4][64];
  {
    int r = tid >> 6, d = tid & 63;
    size_t o = (size_t)(b0 + r) * D_ + d;
    float v = part[o] + part[(size_t)B_ * D_ + o] + b1[d];
    t1[r][d] = fmaxf(v, 0.f);
  }
  __syncthreads();
  if (tid < 128) {
    int r = tid >> 5, j = tid & 31;
    float s = b2[j];
    #pragma unroll 8
    for (int d = 0; d < D_; ++d) s = fmaf(t1[r][d], w2[d * H_ + j], s);
    st[(size_t)(b0 + r) * H_ + j] = fmaxf(s, 0.f);
  }
}

// ---------------------------------------------------------------------------
// K2: w1c[d*1160+j] += sum_{m in quarter} out_w1[m*74240 + d*1160 + j]
// grid (290, 4) x 256; w1c zero-initialized by memset.
__global__ __launch_bounds__(256) void k_w1c(const float* __restrict__ w1,
                                             float* __restrict__ w1c) {
  const int idx = blockIdx.x * 256 + threadIdx.x;  // 0..74239
  const int mq = blockIdx.y;                       // 0..3
  const int m0 = (mq * MED_) >> 2, m1 = ((mq + 1) * MED_) >> 2;
  const float* p = w1 + idx + (size_t)m0 * D_ * HID_;
  float s = 0.f;
  #pragma unroll 8
  for (int m = m0; m < m1; ++m) {
    s += *p;
    p += (size_t)D_ * HID_;
  }
  atomicAdd(&w1c[idx], s);
}

// ---------------------------------------------------------------------------
// K4: per-batch fused. One block (256 thr) per b.
__global__ __launch_bounds__(256) void k_perb(
    const float* __restrict__ glu, const float* __restrict__ tf,
    const float* __restrict__ med, const float* __restrict__ st,
    const float* __restrict__ glu_w, const float* __restrict__ glu_b,
    const float* __restrict__ glu_gate, const float* __restrict__ med_w,
    const float* __restrict__ med_b, const float* __restrict__ med_gate,
    const float* __restrict__ wq, const float* __restrict__ wk,
    const float* __restrict__ wv, const float* __restrict__ wo,
    const float* __restrict__ m2wv, const float* __restrict__ m2wo,
    float* __restrict__ rr) {
  const int b = blockIdx.x;
  const int tid = threadIdx.x;
  const int d = tid & 63;
  const int s4 = tid >> 6;  // 0..3
  __shared__ float xin_s[T_][2 * GLU_];
  __shared__ float y_s[T_][H_];
  __shared__ float gate_s[T_];
  __shared__ float medrow_s[MED_];
  __shared__ float pat_s[28][D_];   // rows 25..27 zero
  __shared__ float q0_s[D_];
  __shared__ float kh_s[T_][D_];
  __shared__ float vh_s[T_][D_];
  __shared__ float sc_s[4][T_];
  __shared__ float at_s[4][T_];
  __shared__ float o_s[D_];
  __shared__ float vec_s[D_];
  __shared__ float red4[4][D_];

  // stage inputs
  for (int e = tid; e < T_ * GLU_; e += 256) {
    int t = e >> 4, i = e & 15;
    xin_s[t][i] = glu[((size_t)b * T_ + t) * GLU_ + i];
    xin_s[t][GLU_ + i] = tf[((size_t)b * T_ + t) * GLU_ + i];
  }
  if (tid < MED_) medrow_s[tid] = med[(size_t)b * T_ * MED_ + tid];
  __syncthreads();

  // y = tanh(xin @ glu_w + glu_b)
  for (int e = tid; e < T_ * H_; e += 256) {
    int t = e >> 5, j = e & 31;
    float s = glu_b[j];
    #pragma unroll 8
    for (int i = 0; i < 2 * GLU_; ++i) s = fmaf(xin_s[t][i], glu_w[i * H_ + j], s);
    y_s[t][j] = tanhf(s);
  }
  __syncthreads();

  // gate partial (tid<200: 8 lane-slices per t) | q0 partial (all 256)
  if (tid < 8 * T_) {
    int t = tid >> 3, sl = tid & 7;
    float s = 0.f;
    #pragma unroll
    for (int i = 0; i < 4; ++i) {
      int j = sl * 4 + i;
      s = fmaf(y_s[t][j], glu_gate[j], s);
    }
    s += __shfl_xor(s, 1);
    s += __shfl_xor(s, 2);
    s += __shfl_xor(s, 4);
    if (sl == 0) gate_s[t] = 1.f / (1.f + __expf(-s));
  }
  {
    float x = 0.f;
    for (int m = s4; m < MED_; m += 4)
      if (medrow_s[m] > 0.9f) x += med_w[m * D_ + d];
    red4[s4][d] = x;
  }
  __syncthreads();

  // q0 finalize (wave 0) and patient fill (all)
  if (tid < D_) {
    float x = med_b[tid] + red4[0][tid] + red4[1][tid] + red4[2][tid] + red4[3][tid];
    float v = x * med_gate[tid];
    #pragma unroll
    for (int off = 32; off > 0; off >>= 1) v += __shfl_xor(v, off);
    q0_s[tid] = x * (1.f / (1.f + __expf(-v)));
  }
  for (int e = tid; e < 28 * H_; e += 256) {
    int t = e >> 5, j = e & 31;
    if (t < T_) {
      pat_s[t][j] = y_s[t][j] * gate_s[t];
      pat_s[t][H_ + j] = st[(size_t)b * H_ + j];
    } else {
      pat_s[t][j] = 0.f;
      pat_s[t][H_ + j] = 0.f;
    }
  }
  __syncthreads();

  // kh, vh: thread (d, s4), t = s4 + 4i; weight values reused across 7 t's
  {
    float aK[7] = {0.f, 0.f, 0.f, 0.f, 0.f, 0.f, 0.f};
    float aV[7] = {0.f, 0.f, 0.f, 0.f, 0.f, 0.f, 0.f};
    #pragma unroll 4
    for (int j = 0; j < D_; ++j) {
      float wkj = wk[j * D_ + d];
      float wvj = wv[j * D_ + d];
      #pragma unroll
      for (int i = 0; i < 7; ++i) {
        float p = pat_s[s4 + 4 * i][j];
        aK[i] = fmaf(p, wkj, aK[i]);
        aV[i] = fmaf(p, wvj, aV[i]);
      }
    }
    #pragma unroll
    for (int i = 0; i < 7; ++i) {
      int t = s4 + 4 * i;
      if (t < T_) { kh_s[t][d] = aK[i]; vh_s[t][d] = aV[i]; }
    }
  }
  // qh partial
  {
    float qp = 0.f;
    #pragma unroll
    for (int i = 0; i < 16; ++i) {
      int j = s4 * 16 + i;
      qp = fmaf(q0_s[j], wq[j * D_ + d], qp);
    }
    red4[s4][d] = qp;
  }
  __syncthreads();
  if (tid < D_) vec_s[tid] = red4[0][tid] + red4[1][tid] + red4[2][tid] + red4[3][tid];  // qh
  __syncthreads();

  // scores (4 heads x 25 keys), scale 1/sqrt(16)
  if (tid < 4 * T_) {
    int h = tid / T_, t = tid - h * T_;
    float s = 0.f;
    #pragma unroll
    for (int i = 0; i < 16; ++i) s = fmaf(vec_s[h * 16 + i], kh_s[t][h * 16 + i], s);
    sc_s[h][t] = s * 0.25f;
  }
  __syncthreads();
  if (tid < 4) {
    float m = -1e30f;
    for (int t = 0; t < T_; ++t) m = fmaxf(m, sc_s[tid][t]);
    float sum = 0.f;
    for (int t = 0; t < T_; ++t) {
      float e = __expf(sc_s[tid][t] - m);
      at_s[tid][t] = e;
      sum += e;
    }
    float inv = 1.f / sum;
    for (int t = 0; t < T_; ++t) at_s[tid][t] *= inv;
  }
  __syncthreads();
  if (tid < D_) {
    int h = tid >> 4;
    float s = 0.f;
    #pragma unroll
    for (int t = 0; t < T_; ++t) s = fmaf(at_s[h][t], vh_s[t][tid], s);
    o_s[tid] = s;
  }
  __syncthreads();
  // e0 = o @ wo
  {
    float p = 0.f;
    #pragma unroll
    for (int i = 0; i < 16; ++i) {
      int j = s4 * 16 + i;
      p = fmaf(o_s[j], wo[j * D_ + d], p);
    }
    red4[s4][d] = p;
  }
  __syncthreads();
  if (tid < D_) vec_s[tid] = red4[0][tid] + red4[1][tid] + red4[2][tid] + red4[3][tid];  // e0
  __syncthreads();
  // t2 = e0 @ m2wv
  {
    float p = 0.f;
    #pragma unroll
    for (int i = 0; i < 16; ++i) {
      int j = s4 * 16 + i;
      p = fmaf(vec_s[j], m2wv[j * D_ + d], p);
    }
    red4[s4][d] = p;
  }
  __syncthreads();
  if (tid < D_) o_s[tid] = red4[0][tid] + red4[1][tid] + red4[2][tid] + red4[3][tid];  // t2
  __syncthreads();
  // rr = relu(t2 @ m2wo)
  {
    float p = 0.f;
    #pragma unroll
    for (int i = 0; i < 16; ++i) {
      int j = s4 * 16 + i;
      p = fmaf(o_s[j], m2wo[j * D_ + d], p);
    }
    red4[s4][d] = p;
  }
  __syncthreads();
  if (tid < D_) {
    float v = red4[0][tid] + red4[1][tid] + red4[2][tid] + red4[3][tid];
    rr[(size_t)b * D_ + tid] = fmaxf(v, 0.f);
  }
}

// ---------------------------------------------------------------------------
// K5: fused final MLP, row-tiled. grid (64 rowtiles, 4 hid-quarters) x 640.
// Phase 1: hid quarter (16 x 290) = relu(rr@w1c+b1); thread (jj, row-octet).
// Phase 2: partial out (16 x 145) over this quarter; thread (n, row-quad);
//          atomicAdd into out (zero-initialized); jq==0 adds bias.
__global__ __launch_bounds__(640) void k_final(
    const float* __restrict__ rr, const float* __restrict__ w1c,
    const float* __restrict__ b1, const float* __restrict__ w2,
    const float* __restrict__ b2, float* __restrict__ out) {
  const int tid = threadIdx.x;
  const int b0 = blockIdx.x * 16;
  const int jq = blockIdx.y;
  const int j0 = jq * 290;
  __shared__ float rr_s[16][D_];     // 4 KB
  __shared__ float hid_s[16][292];   // 18.7 KB (rows 16B-aligned)
  for (int e = tid; e < 16 * D_; e += 640)
    ((float*)rr_s)[e] = rr[(size_t)b0 * D_ + e];
  __syncthreads();
  // phase 1
  if (tid < 580) {
    int jj = tid % 290, rh = tid / 290;  // rh: rows rh*8..rh*8+7
    const float* wp = w1c + (size_t)(j0 + jj);
    float bb = b1[j0 + jj];
    float acc[8] = {0.f, 0.f, 0.f, 0.f, 0.f, 0.f, 0.f, 0.f};
    #pragma unroll 4
    for (int d4 = 0; d4 < 16; ++d4) {
      float w0 = wp[(size_t)(4 * d4 + 0) * HID_];
      float w1v = wp[(size_t)(4 * d4 + 1) * HID_];
      float w2v = wp[(size_t)(4 * d4 + 2) * HID_];
      float w3v = wp[(size_t)(4 * d4 + 3) * HID_];
      #pragma unroll
      for (int r8 = 0; r8 < 8; ++r8) {
        float4 rv = *(const float4*)&rr_s[rh * 8 + r8][4 * d4];
        acc[r8] += rv.x * w0 + rv.y * w1v + rv.z * w2v + rv.w * w3v;
      }
    }
    #pragma unroll
    for (int r8 = 0; r8 < 8; ++r8)
      hid_s[rh * 8 + r8][jj] = fmaxf(acc[r8] + bb, 0.f);
  }
  __syncthreads();
  // phase 2
  if (tid < 580) {
    int n = tid % MED_, rg = tid / MED_;  // rg: rows rg*4..rg*4+3
    const float* w2p = w2 + (size_t)j0 * MED_ + n;
    float s0 = 0.f, s1 = 0.f, s2 = 0.f, s3 = 0.f;
    #pragma unroll 4
    for (int jv = 0; jv < 72; ++jv) {
      float wa = w2p[(size_t)(4 * jv + 0) * MED_];
      float wb = w2p[(size_t)(4 * jv + 1) * MED_];
      float wc = w2p[(size_t)(4 * jv + 2) * MED_];
      float wd = w2p[(size_t)(4 * jv + 3) * MED_];
      float4 h0 = *(const float4*)&hid_s[rg * 4 + 0][4 * jv];
      float4 h1 = *(const float4*)&hid_s[rg * 4 + 1][4 * jv];
      float4 h2 = *(const float4*)&hid_s[rg * 4 + 2][4 * jv];
      float4 h3 = *(const float4*)&hid_s[rg * 4 + 3][4 * jv];
      s0 += h0.x * wa + h0.y * wb + h0.z * wc + h0.w * wd;
      s1 += h1.x * wa + h1.y * wb + h1.z * wc + h1.w * wd;
      s2 += h2.x * wa + h2.y * wb + h2.z * wc + h2.w * wd;
      s3 += h3.x * wa + h3.y * wb + h3.z * wc + h3.w * wd;
    }
    {  // tail j = 288, 289
      float wa = w2p[(size_t)288 * MED_];
      float wb = w2p[(size_t)289 * MED_];
      s0 += hid_s[rg * 4 + 0][288] * wa + hid_s[rg * 4 + 0][289] * wb;
      s1 += hid_s[rg * 4 + 1][288] * wa + hid_s[rg * 4 + 1][289] * wb;
      s2 += hid_s[rg * 4 + 2][288] * wa + hid_s[rg * 4 + 2][289] * wb;
      s3 += hid_s[rg * 4 + 3][288] * wa + hid_s[rg * 4 + 3][289] * wb;
    }
    float bias = (jq == 0) ? b2[n] : 0.f;
    atomicAdd(&out[(size_t)(b0 + rg * 4 + 0) * MED_ + n], s0 + bias);
    atomicAdd(&out[(size_t)(b0 + rg * 4 + 1) * MED_ + n], s1 + bias);
    atomicAdd(&out[(size_t)(b0 + rg * 4 + 2) * MED_ + n], s2 + bias);
    atomicAdd(&out[(size_t)(b0 + rg * 4 + 3) * MED_ + n], s3 + bias);
  }
}

// ---------------------------------------------------------------------------
extern "C" void kernel_launch(void* const* d_in, const int* in_sizes, int n_in,
                              void* d_out, int out_size, void* d_ws, size_t ws_size,
                              hipStream_t stream) {
  (void)in_sizes; (void)n_in; (void)out_size; (void)ws_size;
  const float* lab      = (const float*)d_in[0];
  const float* glu      = (const float*)d_in[1];
  const float* tf       = (const float*)d_in[2];
  const float* med      = (const float*)d_in[3];
  const float* sll_w1   = (const float*)d_in[7];
  const float* sll_b1   = (const float*)d_in[8];
  const float* sll_w2   = (const float*)d_in[9];
  const float* sll_b2   = (const float*)d_in[10];
  const float* glu_w    = (const float*)d_in[11];
  const float* glu_b    = (const float*)d_in[12];
  const float* glu_gate = (const float*)d_in[13];
  const float* med_w    = (const float*)d_in[14];
  const float* med_b    = (const float*)d_in[15];
  const float* med_gate = (const float*)d_in[16];
  const float* m1_wq    = (const float*)d_in[27];
  const float* m1_wk    = (const float*)d_in[28];
  const float* m1_wv    = (const float*)d_in[29];
  const float* m1_wo    = (const float*)d_in[30];
  const float* m2_wv    = (const float*)d_in[33];
  const float* m2_wo    = (const float*)d_in[34];
  const float* out_w1   = (const float*)d_in[35];
  const float* out_b1   = (const float*)d_in[36];
  const float* out_w2   = (const float*)d_in[37];
  const float* out_b2   = (const float*)d_in[38];
  float* out = (float*)d_out;

  float* ws   = (float*)d_ws;
  float* st   = ws;                      // 1024*32   = 32768
  float* rr   = st + B_ * H_;            // 1024*64   = 65536
  float* w1c  = rr + B_ * D_;            // 64*1160   = 74240
  float* part = w1c + D_ * HID_;         // 2*1024*64 = 131072

  hipLaunchKernelGGL(k_static_a, dim3(B_ / 8, 2), dim3(512), 0, stream,
                     lab, sll_w1, part);
  hipLaunchKernelGGL(k_static_b, dim3(B_ / 4), dim3(256), 0, stream,
                     part, sll_b1, sll_w2, sll_b2, st);
  hipMemsetAsync(w1c, 0, (size_t)D_ * HID_ * sizeof(float), stream);
  hipMemsetAsync(out, 0, (size_t)B_ * MED_ * sizeof(float), stream);
  hipLaunchKernelGGL(k_w1c, dim3((D_ * HID_) / 256, 4), dim3(256), 0, stream,
                     out_w1, w1c);
  hipLaunchKernelGGL(k_perb, dim3(B_), dim3(256), 0, stream,
                     glu, tf, med, st, glu_w, glu_b, glu_gate,
                     med_w, med_b, med_gate,
                     m1_wq, m1_wk, m1_wv, m1_wo, m2_wv, m2_wo, rr);
  hipLaunchKernelGGL(k_final, dim3(B_ / 16, 4), dim3(640), 0, stream,
                     rr, w1c, out_b1, out_w2, out_b2, out);
}